// Round 3
// baseline (139.258 us; speedup 1.0000x reference)
//
#include <hip/hip_runtime.h>
#include <math.h>

#define B    64
#define DQ   512
#define DO   256
#define NH   8
#define DH   32
#define HW   1024
#define NCH  16     // s-chunks per image
#define CHS  64     // s per chunk

// ---------------------------------------------------------------- kA: qv = qW^T+b, folded into kc/kd weights
__global__ void kA(const float* __restrict__ q,    const float* __restrict__ w_q,
                   const float* __restrict__ b_q,
                   const float* __restrict__ w_kc, const float* __restrict__ b_kc,
                   const float* __restrict__ w_kd, const float* __restrict__ b_kd,
                   const float* __restrict__ temp_c, const float* __restrict__ temp_d,
                   float* __restrict__ wqkc, float* __restrict__ wqkd,
                   float* __restrict__ qbc,  float* __restrict__ qbd) {
    __shared__ float qs[DQ];
    __shared__ float qvs[DO];
    int b = blockIdx.x, t = threadIdx.x;
    qs[t]       = q[b*DQ + t];
    qs[t + 256] = q[b*DQ + t + 256];
    __syncthreads();
    float acc = b_q[t];
    const float4* w4 = reinterpret_cast<const float4*>(w_q + t*DQ);
    #pragma unroll 4
    for (int k = 0; k < DQ/4; ++k) {
        float4 w = w4[k];
        acc += qs[4*k]*w.x + qs[4*k+1]*w.y + qs[4*k+2]*w.z + qs[4*k+3]*w.w;
    }
    qvs[t] = acc;
    __syncthreads();
    float itc = 1.0f/temp_c[0], itd = 1.0f/temp_d[0];
    for (int idx = t; idx < NH*DO; idx += 256) {
        int n = idx >> 8, c = idx & 255;
        float ac = 0.f, ad = 0.f;
        #pragma unroll
        for (int d = 0; d < DH; ++d) {
            float qd = qvs[n*DH + d];
            ac += qd * w_kc[(n*DH + d)*DO + c];
            ad += qd * w_kd[(n*DH + d)*DO + c];
        }
        wqkc[(b*NH + n)*DO + c] = ac*itc;
        wqkd[(b*NH + n)*DO + c] = ad*itd;
    }
    if (t < 16) {
        int n = t & 7;
        float s = 0.f;
        if (t < 8) { for (int d = 0; d < DH; ++d) s += qvs[n*DH+d]*b_kc[n*DH+d]; qbc[b*NH+n] = s*itc; }
        else       { for (int d = 0; d < DH; ++d) s += qvs[n*DH+d]*b_kd[n*DH+d]; qbd[b*NH+n] = s*itd; }
    }
}

// ---------------------------------------------------------------- k3F: logits + gate + block-local softmax + partial pool
// grid (NCH, B), block 256. One v pass.
__global__ void k3F(const float* __restrict__ v,
                    const float* __restrict__ wqkc, const float* __restrict__ wqkd,
                    const float* __restrict__ qbc,  const float* __restrict__ qbd,
                    float* __restrict__ gate, float* __restrict__ pvp,
                    float* __restrict__ mz) {
    __shared__ float smem[4*NH*DO];        // 32 KB: phase1 red (16 KB) then pool partials (32 KB)
    __shared__ float l_lds[NH][CHS];
    __shared__ float e_lds[NH][CHS];
    int ch = blockIdx.x, b = blockIdx.y;
    int t = threadIdx.x;
    int s0 = ch*CHS;
    int bn0 = b*NH;

    // ---- phase 1: partial logits over c-quarter, coalesced in s
    {
        int sl = t & 63, csub = t >> 6;
        const float* vb = v + (size_t)b*DO*HW + s0 + sl;
        const float* wc = wqkc + bn0*DO;
        const float* wd = wqkd + bn0*DO;
        float ac[NH] = {0,0,0,0,0,0,0,0};
        float ad[NH] = {0,0,0,0,0,0,0,0};
        for (int c0 = csub*64; c0 < csub*64 + 64; c0 += 4) {
            float v0 = vb[(size_t)(c0+0)*HW];
            float v1 = vb[(size_t)(c0+1)*HW];
            float v2 = vb[(size_t)(c0+2)*HW];
            float v3 = vb[(size_t)(c0+3)*HW];
            #pragma unroll
            for (int n = 0; n < NH; ++n) {
                ac[n] += v0*wc[n*DO+c0] + v1*wc[n*DO+c0+1] + v2*wc[n*DO+c0+2] + v3*wc[n*DO+c0+3];
                ad[n] += v0*wd[n*DO+c0] + v1*wd[n*DO+c0+1] + v2*wd[n*DO+c0+2] + v3*wd[n*DO+c0+3];
            }
        }
        #pragma unroll
        for (int n = 0; n < NH; ++n) {
            smem[((csub*2+0)*NH + n)*CHS + sl] = ac[n];
            smem[((csub*2+1)*NH + n)*CHS + sl] = ad[n];
        }
    }
    __syncthreads();

    // ---- phase 2: reduce csub partials, write gate, keep logits in LDS
    for (int idx = t; idx < NH*CHS; idx += 256) {
        int n = idx >> 6, s = idx & 63;
        float lc = qbc[bn0+n], ld = qbd[bn0+n];
        #pragma unroll
        for (int k = 0; k < 4; ++k) {
            lc += smem[((k*2+0)*NH + n)*CHS + s];
            ld += smem[((k*2+1)*NH + n)*CHS + s];
        }
        l_lds[n][s] = lc;
        gate[(bn0+n)*HW + s0 + s] = 1.0f/(1.0f + __expf(-ld));
    }
    __syncthreads();

    // ---- phase 3: per-head block max / exp / partial Z
    {
        int g = t >> 5, l32 = t & 31;
        float x0 = l_lds[g][l32], x1 = l_lds[g][l32+32];
        float m = fmaxf(x0, x1);
        #pragma unroll
        for (int k = 16; k > 0; k >>= 1) m = fmaxf(m, __shfl_xor(m, k, 32));
        float e0 = __expf(x0 - m), e1 = __expf(x1 - m);
        e_lds[g][l32]      = e0;
        e_lds[g][l32 + 32] = e1;
        float z = e0 + e1;
        #pragma unroll
        for (int k = 16; k > 0; k >>= 1) z += __shfl_xor(z, k, 32);
        if (l32 == 0) {
            float* mzp = mz + ((size_t)(b*NCH + ch)*NH + g)*2;
            mzp[0] = m; mzp[1] = z;
        }
    }
    __syncthreads();

    // ---- phase 4: partial pool P[n][c] = sum_sl e[n][sl] * v[c][sl]  (v re-read, L2-hot)
    {
        int cb = t & 63, slq = t >> 6;              // slq wave-uniform
        const float* vr = v + (size_t)b*DO*HW + s0 + slq*16;
        float pacc[4][NH];
        #pragma unroll
        for (int r = 0; r < 4; ++r)
            #pragma unroll
            for (int n = 0; n < NH; ++n) pacc[r][n] = 0.f;
        #pragma unroll
        for (int i4 = 0; i4 < 4; ++i4) {
            float4 vv[4];
            #pragma unroll
            for (int r = 0; r < 4; ++r) {
                int c = cb + 64*r;
                vv[r] = *reinterpret_cast<const float4*>(vr + (size_t)c*HW + i4*4);
            }
            #pragma unroll
            for (int n = 0; n < NH; ++n) {
                float4 e4 = *reinterpret_cast<const float4*>(&e_lds[n][slq*16 + i4*4]); // broadcast
                #pragma unroll
                for (int r = 0; r < 4; ++r)
                    pacc[r][n] += vv[r].x*e4.x + vv[r].y*e4.y + vv[r].z*e4.z + vv[r].w*e4.w;
            }
        }
        #pragma unroll
        for (int n = 0; n < NH; ++n)
            #pragma unroll
            for (int r = 0; r < 4; ++r)
                smem[(slq*NH + n)*DO + cb + 64*r] = pacc[r][n];
    }
    __syncthreads();
    for (int idx = t; idx < NH*DO; idx += 256) {
        float sum = smem[idx] + smem[NH*DO + idx] + smem[2*NH*DO + idx] + smem[3*NH*DO + idx];
        pvp[(size_t)(b*NCH + ch)*NH*DO + idx] = sum;
    }
}

// ---------------------------------------------------------------- k4C: combine chunks + attn = w_v·pv + b_v
__global__ void k4C(const float* __restrict__ pvp, const float* __restrict__ mz,
                    const float* __restrict__ w_v, const float* __restrict__ b_v,
                    float* __restrict__ attn) {
    __shared__ float scale[NCH][NH];
    __shared__ float pv_lds[NH][DO];
    int b = blockIdx.x, t = threadIdx.x;
    if (t < NH) {
        int n = t;
        float M = -1e30f;
        for (int ch = 0; ch < NCH; ++ch)
            M = fmaxf(M, mz[((size_t)(b*NCH + ch)*NH + n)*2]);
        float Z = 0.f;
        for (int ch = 0; ch < NCH; ++ch) {
            float m = mz[((size_t)(b*NCH + ch)*NH + n)*2];
            float z = mz[((size_t)(b*NCH + ch)*NH + n)*2 + 1];
            float sc = __expf(m - M);
            scale[ch][n] = sc;
            Z += sc*z;
        }
        float inv = 1.0f/Z;
        for (int ch = 0; ch < NCH; ++ch) scale[ch][n] *= inv;
    }
    __syncthreads();
    {
        int c = t;
        #pragma unroll
        for (int n = 0; n < NH; ++n) {
            float acc = 0.f;
            #pragma unroll 4
            for (int ch = 0; ch < NCH; ++ch)
                acc += scale[ch][n] * pvp[((size_t)(b*NCH + ch)*NH + n)*DO + c];
            pv_lds[n][c] = acc;
        }
    }
    __syncthreads();
    {
        int n = t >> 5;
        float acc = b_v[t];
        const float4* w4 = reinterpret_cast<const float4*>(w_v + t*DO);
        #pragma unroll 4
        for (int c4 = 0; c4 < DO/4; ++c4) {
            float4 w = w4[c4];
            int c = c4*4;
            acc += pv_lds[n][c]*w.x + pv_lds[n][c+1]*w.y + pv_lds[n][c+2]*w.z + pv_lds[n][c+3]*w.w;
        }
        attn[b*DO + t] = acc;
    }
}

// ---------------------------------------------------------------- k5: out = leaky(bn(gate[s^T]*attn + v))
__global__ void k5_out(const float* __restrict__ v, const float* __restrict__ gate,
                       const float* __restrict__ attn,
                       const float* __restrict__ bn_g, const float* __restrict__ bn_b,
                       const float* __restrict__ bn_m, const float* __restrict__ bn_v,
                       float* __restrict__ out) {
    int c = blockIdx.x, b = blockIdx.y;
    int n = c >> 5, d = c & 31;
    int t = threadIdx.x;
    __shared__ float g[32*33];             // stride 33 kills transpose bank conflicts
    float4 gv = reinterpret_cast<const float4*>(gate + (b*NH + n)*HW)[t];
    int s0 = t*4;
    int ga = s0 >> 5, gb = s0 & 31;
    g[ga*33 + gb + 0] = gv.x;
    g[ga*33 + gb + 1] = gv.y;
    g[ga*33 + gb + 2] = gv.z;
    g[ga*33 + gb + 3] = gv.w;
    __syncthreads();
    float av   = attn[(b*NH + n)*DH + d];
    float inv  = bn_g[c] / sqrtf(bn_v[c] + 1e-5f);
    float mean = bn_m[c], beta = bn_b[c];
    size_t base = ((size_t)(b*DO + c))*HW;
    float4 r4 = reinterpret_cast<const float4*>(v + base)[t];
    int l = 4*t;
    int i_ = l >> 5, j_ = l & 31;          // gate index s = j*32 + i
    float x0 = g[(j_+0)*33 + i_]*av + r4.x;
    float x1 = g[(j_+1)*33 + i_]*av + r4.y;
    float x2 = g[(j_+2)*33 + i_]*av + r4.z;
    float x3 = g[(j_+3)*33 + i_]*av + r4.w;
    float y0 = (x0 - mean)*inv + beta; y0 = y0 >= 0.f ? y0 : 0.1f*y0;
    float y1 = (x1 - mean)*inv + beta; y1 = y1 >= 0.f ? y1 : 0.1f*y1;
    float y2 = (x2 - mean)*inv + beta; y2 = y2 >= 0.f ? y2 : 0.1f*y2;
    float y3 = (x3 - mean)*inv + beta; y3 = y3 >= 0.f ? y3 : 0.1f*y3;
    reinterpret_cast<float4*>(out + base)[t] = make_float4(y0, y1, y2, y3);
}

// ----------------------------------------------------------------
extern "C" void kernel_launch(void* const* d_in, const int* in_sizes, int n_in,
                              void* d_out, int out_size, void* d_ws, size_t ws_size,
                              hipStream_t stream) {
    const float* q      = (const float*)d_in[0];
    const float* v      = (const float*)d_in[1];
    const float* w_q    = (const float*)d_in[2];
    const float* b_q    = (const float*)d_in[3];
    const float* w_kc   = (const float*)d_in[4];
    const float* b_kc   = (const float*)d_in[5];
    const float* w_kd   = (const float*)d_in[6];
    const float* b_kd   = (const float*)d_in[7];
    const float* w_v    = (const float*)d_in[8];
    const float* b_v    = (const float*)d_in[9];
    const float* temp_c = (const float*)d_in[10];
    const float* temp_d = (const float*)d_in[11];
    const float* bn_g   = (const float*)d_in[12];
    const float* bn_b   = (const float*)d_in[13];
    const float* bn_m   = (const float*)d_in[14];
    const float* bn_v   = (const float*)d_in[15];
    float* out = (float*)d_out;

    float* ws   = (float*)d_ws;
    float* wqkc = ws;                     // B*NH*DO      = 131072
    float* wqkd = wqkc + B*NH*DO;         // 131072
    float* qbc  = wqkd + B*NH*DO;         // 512
    float* qbd  = qbc  + B*NH;            // 512
    float* gate = qbd  + B*NH;            // B*NH*HW      = 524288
    float* pvp  = gate + B*NH*HW;         // B*NCH*NH*DO  = 2097152
    float* mz   = pvp  + B*NCH*NH*DO;     // B*NCH*NH*2   = 16384
    float* attn = mz   + B*NCH*NH*2;      // B*DO         = 16384

    kA   <<<B,             256, 0, stream>>>(q, w_q, b_q, w_kc, b_kc, w_kd, b_kd,
                                             temp_c, temp_d, wqkc, wqkd, qbc, qbd);
    k3F  <<<dim3(NCH, B),  256, 0, stream>>>(v, wqkc, wqkd, qbc, qbd, gate, pvp, mz);
    k4C  <<<B,             256, 0, stream>>>(pvp, mz, w_v, b_v, attn);
    k5_out<<<dim3(DO, B),  256, 0, stream>>>(v, gate, attn, bn_g, bn_b, bn_m, bn_v, out);
}

// Round 4
// 119.419 us; speedup vs baseline: 1.1661x; 1.1661x over previous
//
#include <hip/hip_runtime.h>
#include <math.h>

#define B    64
#define DQ   512
#define DO   256
#define NH   8
#define DH   32
#define HW   1024
#define NCH  16     // s-chunks per image
#define CHS  64     // s per chunk

// ---------------------------------------------------------------- kA: qv = qW^T+b, folded into kc/kd weights
__global__ void kA(const float* __restrict__ q,    const float* __restrict__ w_q,
                   const float* __restrict__ b_q,
                   const float* __restrict__ w_kc, const float* __restrict__ b_kc,
                   const float* __restrict__ w_kd, const float* __restrict__ b_kd,
                   const float* __restrict__ temp_c, const float* __restrict__ temp_d,
                   float* __restrict__ wqkc, float* __restrict__ wqkd,
                   float* __restrict__ qbc,  float* __restrict__ qbd) {
    __shared__ float qs[DQ];
    __shared__ float qvs[DO];
    int b = blockIdx.x, t = threadIdx.x;
    qs[t]       = q[b*DQ + t];
    qs[t + 256] = q[b*DQ + t + 256];
    __syncthreads();
    float acc = b_q[t];
    const float4* w4 = reinterpret_cast<const float4*>(w_q + t*DQ);
    #pragma unroll 4
    for (int k = 0; k < DQ/4; ++k) {
        float4 w = w4[k];
        acc += qs[4*k]*w.x + qs[4*k+1]*w.y + qs[4*k+2]*w.z + qs[4*k+3]*w.w;
    }
    qvs[t] = acc;
    __syncthreads();
    float itc = 1.0f/temp_c[0], itd = 1.0f/temp_d[0];
    for (int idx = t; idx < NH*DO; idx += 256) {
        int n = idx >> 8, c = idx & 255;
        float ac = 0.f, ad = 0.f;
        #pragma unroll
        for (int d = 0; d < DH; ++d) {
            float qd = qvs[n*DH + d];
            ac += qd * w_kc[(n*DH + d)*DO + c];
            ad += qd * w_kd[(n*DH + d)*DO + c];
        }
        wqkc[(b*NH + n)*DO + c] = ac*itc;
        wqkd[(b*NH + n)*DO + c] = ad*itd;
    }
    if (t < 16) {
        int n = t & 7;
        float s = 0.f;
        if (t < 8) { for (int d = 0; d < DH; ++d) s += qvs[n*DH+d]*b_kc[n*DH+d]; qbc[b*NH+n] = s*itc; }
        else       { for (int d = 0; d < DH; ++d) s += qvs[n*DH+d]*b_kd[n*DH+d]; qbd[b*NH+n] = s*itd; }
    }
}

// ---------------------------------------------------------------- k3: logits + gate + block-local softmax stats
// grid (NCH, B), block 512 (8 waves). 4 blocks/CU * 8 waves = 32 waves/CU.
__global__ __launch_bounds__(512, 8)
void k3(const float* __restrict__ v,
        const float* __restrict__ wqkc, const float* __restrict__ wqkd,
        const float* __restrict__ qbc,  const float* __restrict__ qbd,
        float* __restrict__ gate, float* __restrict__ ebuf, float* __restrict__ mz) {
    __shared__ float pc[8*NH*CHS];   // [csub][n][s]  16 KB
    __shared__ float pd[8*NH*CHS];   // 16 KB
    int ch = blockIdx.x, b = blockIdx.y;
    int t  = threadIdx.x;
    int s0 = ch*CHS;
    int bn0 = b*NH;
    int sl = t & 63;
    int csub = __builtin_amdgcn_readfirstlane(t >> 6);   // wave-uniform -> scalar weight loads

    // ---- phase 1: partial logits, csub-wave owns 32 channels, lanes over s (coalesced)
    {
        const float* vb = v + (size_t)b*DO*HW + s0 + sl;
        const float* wc = wqkc + bn0*DO;
        const float* wd = wqkd + bn0*DO;
        float ac[NH] = {0,0,0,0,0,0,0,0};
        float ad[NH] = {0,0,0,0,0,0,0,0};
        int cbase = csub*32;
        for (int c0 = cbase; c0 < cbase + 32; c0 += 4) {
            float v0 = vb[(size_t)(c0+0)*HW];
            float v1 = vb[(size_t)(c0+1)*HW];
            float v2 = vb[(size_t)(c0+2)*HW];
            float v3 = vb[(size_t)(c0+3)*HW];
            #pragma unroll
            for (int n = 0; n < NH; ++n) {
                ac[n] += v0*wc[n*DO+c0] + v1*wc[n*DO+c0+1] + v2*wc[n*DO+c0+2] + v3*wc[n*DO+c0+3];
                ad[n] += v0*wd[n*DO+c0] + v1*wd[n*DO+c0+1] + v2*wd[n*DO+c0+2] + v3*wd[n*DO+c0+3];
            }
        }
        #pragma unroll
        for (int n = 0; n < NH; ++n) {
            pc[(csub*NH + n)*CHS + sl] = ac[n];
            pd[(csub*NH + n)*CHS + sl] = ad[n];
        }
    }
    __syncthreads();

    // ---- phase 2: reduce csubs; wave n owns head n; gate + e + (m,z)
    {
        int n = csub, s = sl;
        float lc = qbc[bn0+n], ld = qbd[bn0+n];
        #pragma unroll
        for (int k = 0; k < 8; ++k) {
            lc += pc[(k*NH + n)*CHS + s];
            ld += pd[(k*NH + n)*CHS + s];
        }
        gate[(bn0+n)*HW + s0 + s] = 1.0f/(1.0f + __expf(-ld));
        float m = lc;
        #pragma unroll
        for (int k = 32; k > 0; k >>= 1) m = fmaxf(m, __shfl_xor(m, k));
        float e = __expf(lc - m);
        ebuf[(bn0+n)*HW + s0 + s] = e;
        float z = e;
        #pragma unroll
        for (int k = 32; k > 0; k >>= 1) z += __shfl_xor(z, k);
        if (s == 0) {
            float* mzp = mz + ((size_t)(b*NCH + ch)*NH + n)*2;
            mzp[0] = m; mzp[1] = z;
        }
    }
}

// ---------------------------------------------------------------- kP: normalized pool P[b,n,c] = sum_s p v  (v L3-hot)
// grid (8 c-groups, B), block 256 (4 waves). One float4/lane = one 4KB row per wave.
__global__ void kP(const float* __restrict__ v, const float* __restrict__ ebuf,
                   const float* __restrict__ mz, float* __restrict__ P) {
    __shared__ float p_lds[NH*HW];       // 32 KB normalized probs
    __shared__ float scale[NCH*NH];
    int cg = blockIdx.x, b = blockIdx.y;
    int t = threadIdx.x;
    if (t < NH) {
        int n = t;
        float M = -1e30f;
        for (int ch = 0; ch < NCH; ++ch)
            M = fmaxf(M, mz[((size_t)(b*NCH+ch)*NH+n)*2]);
        float Z = 0.f;
        for (int ch = 0; ch < NCH; ++ch) {
            float sc = __expf(mz[((size_t)(b*NCH+ch)*NH+n)*2] - M);
            Z += sc * mz[((size_t)(b*NCH+ch)*NH+n)*2 + 1];
            scale[ch*NH+n] = sc;
        }
        float inv = 1.0f/Z;
        for (int ch = 0; ch < NCH; ++ch) scale[ch*NH+n] *= inv;
    }
    __syncthreads();
    #pragma unroll
    for (int it = 0; it < 8; ++it) {
        int g = it*1024 + t*4;           // covers NH*HW = 8192 floats
        int n = g >> 10, s = g & 1023;
        float4 e4 = *reinterpret_cast<const float4*>(ebuf + (size_t)(b*NH+n)*HW + s);
        float sc = scale[(s>>6)*NH + n];
        *reinterpret_cast<float4*>(p_lds + g) = make_float4(e4.x*sc, e4.y*sc, e4.z*sc, e4.w*sc);
    }
    __syncthreads();
    int w = __builtin_amdgcn_readfirstlane(t >> 6), lane = t & 63;
    for (int r = 0; r < 8; ++r) {
        int c = cg*32 + w*8 + r;
        float4 v4 = *reinterpret_cast<const float4*>(v + ((size_t)(b*DO+c))*HW + lane*4);
        float red[NH];
        #pragma unroll
        for (int n = 0; n < NH; ++n) {
            float4 p4 = *reinterpret_cast<const float4*>(p_lds + n*HW + lane*4);
            red[n] = v4.x*p4.x + v4.y*p4.y + v4.z*p4.z + v4.w*p4.w;
        }
        #pragma unroll
        for (int n = 0; n < NH; ++n) {
            float x = red[n];
            #pragma unroll
            for (int k = 32; k > 0; k >>= 1) x += __shfl_xor(x, k);
            red[n] = x;
        }
        if (lane == 0) {
            #pragma unroll
            for (int n = 0; n < NH; ++n) P[(size_t)(b*NH+n)*DO + c] = red[n];
        }
    }
}

// ---------------------------------------------------------------- k4c: attn = w_v . P + b_v
__global__ void k4c(const float* __restrict__ P, const float* __restrict__ w_v,
                    const float* __restrict__ b_v, float* __restrict__ attn) {
    __shared__ float pv_lds[NH*DO];
    int b = blockIdx.x, t = threadIdx.x;
    for (int i = t; i < NH*DO; i += 256) pv_lds[i] = P[(size_t)b*NH*DO + i];
    __syncthreads();
    int n = t >> 5;
    float acc = b_v[t];
    const float4* w4 = reinterpret_cast<const float4*>(w_v + t*DO);
    #pragma unroll 4
    for (int c4 = 0; c4 < DO/4; ++c4) {
        float4 wv = w4[c4];
        int c = c4*4;
        acc += pv_lds[n*DO+c]*wv.x + pv_lds[n*DO+c+1]*wv.y + pv_lds[n*DO+c+2]*wv.z + pv_lds[n*DO+c+3]*wv.w;
    }
    attn[b*DO + t] = acc;
}

// ---------------------------------------------------------------- k5: out = leaky(bn(gate[s^T]*attn + v))
__global__ void k5_out(const float* __restrict__ v, const float* __restrict__ gate,
                       const float* __restrict__ attn,
                       const float* __restrict__ bn_g, const float* __restrict__ bn_b,
                       const float* __restrict__ bn_m, const float* __restrict__ bn_v,
                       float* __restrict__ out) {
    int c = blockIdx.x, b = blockIdx.y;
    int n = c >> 5, d = c & 31;
    int t = threadIdx.x;
    __shared__ float g[32*33];             // stride 33 kills transpose bank conflicts
    float4 gv = reinterpret_cast<const float4*>(gate + (b*NH + n)*HW)[t];
    int s0 = t*4;
    int ga = s0 >> 5, gb = s0 & 31;
    g[ga*33 + gb + 0] = gv.x;
    g[ga*33 + gb + 1] = gv.y;
    g[ga*33 + gb + 2] = gv.z;
    g[ga*33 + gb + 3] = gv.w;
    __syncthreads();
    float av   = attn[(b*NH + n)*DH + d];
    float inv  = bn_g[c] / sqrtf(bn_v[c] + 1e-5f);
    float mean = bn_m[c], beta = bn_b[c];
    size_t base = ((size_t)(b*DO + c))*HW;
    float4 r4 = reinterpret_cast<const float4*>(v + base)[t];
    int l = 4*t;
    int i_ = l >> 5, j_ = l & 31;          // gate index s = j*32 + i
    float x0 = g[(j_+0)*33 + i_]*av + r4.x;
    float x1 = g[(j_+1)*33 + i_]*av + r4.y;
    float x2 = g[(j_+2)*33 + i_]*av + r4.z;
    float x3 = g[(j_+3)*33 + i_]*av + r4.w;
    float y0 = (x0 - mean)*inv + beta; y0 = y0 >= 0.f ? y0 : 0.1f*y0;
    float y1 = (x1 - mean)*inv + beta; y1 = y1 >= 0.f ? y1 : 0.1f*y1;
    float y2 = (x2 - mean)*inv + beta; y2 = y2 >= 0.f ? y2 : 0.1f*y2;
    float y3 = (x3 - mean)*inv + beta; y3 = y3 >= 0.f ? y3 : 0.1f*y3;
    reinterpret_cast<float4*>(out + base)[t] = make_float4(y0, y1, y2, y3);
}

// ----------------------------------------------------------------
extern "C" void kernel_launch(void* const* d_in, const int* in_sizes, int n_in,
                              void* d_out, int out_size, void* d_ws, size_t ws_size,
                              hipStream_t stream) {
    const float* q      = (const float*)d_in[0];
    const float* v      = (const float*)d_in[1];
    const float* w_q    = (const float*)d_in[2];
    const float* b_q    = (const float*)d_in[3];
    const float* w_kc   = (const float*)d_in[4];
    const float* b_kc   = (const float*)d_in[5];
    const float* w_kd   = (const float*)d_in[6];
    const float* b_kd   = (const float*)d_in[7];
    const float* w_v    = (const float*)d_in[8];
    const float* b_v    = (const float*)d_in[9];
    const float* temp_c = (const float*)d_in[10];
    const float* temp_d = (const float*)d_in[11];
    const float* bn_g   = (const float*)d_in[12];
    const float* bn_b   = (const float*)d_in[13];
    const float* bn_m   = (const float*)d_in[14];
    const float* bn_v   = (const float*)d_in[15];
    float* out = (float*)d_out;

    float* ws   = (float*)d_ws;
    float* wqkc = ws;                     // B*NH*DO     = 131072
    float* wqkd = wqkc + B*NH*DO;         // 131072
    float* qbc  = wqkd + B*NH*DO;         // 512
    float* qbd  = qbc  + B*NH;            // 512
    float* gate = qbd  + B*NH;            // B*NH*HW     = 524288
    float* ebuf = gate + B*NH*HW;         // 524288
    float* mz   = ebuf + B*NH*HW;         // B*NCH*NH*2  = 16384
    float* P    = mz   + B*NCH*NH*2;      // B*NH*DO     = 131072
    float* attn = P    + B*NH*DO;         // B*DO        = 16384

    kA    <<<B,             256, 0, stream>>>(q, w_q, b_q, w_kc, b_kc, w_kd, b_kd,
                                              temp_c, temp_d, wqkc, wqkd, qbc, qbd);
    k3    <<<dim3(NCH, B),  512, 0, stream>>>(v, wqkc, wqkd, qbc, qbd, gate, ebuf, mz);
    kP    <<<dim3(8, B),    256, 0, stream>>>(v, ebuf, mz, P);
    k4c   <<<B,             256, 0, stream>>>(P, w_v, b_v, attn);
    k5_out<<<dim3(DO, B),   256, 0, stream>>>(v, gate, attn, bn_g, bn_b, bn_m, bn_v, out);
}

// Round 5
// 109.026 us; speedup vs baseline: 1.2773x; 1.0953x over previous
//
#include <hip/hip_runtime.h>
#include <math.h>

#define B    64
#define DQ   512
#define DO   256
#define NH   8
#define DH   32
#define HW   1024
#define NCH  16     // s-chunks per image
#define CHS  64     // s per chunk

// ---------------------------------------------------------------- k1: qv = q @ w_q.T + b_q   (wave-per-output GEMV)
// grid (16, B), block 256 = 4 waves; each wave does 4 outputs.
__global__ __launch_bounds__(256) void k1_qv(const float* __restrict__ q,
                                             const float* __restrict__ w_q,
                                             const float* __restrict__ b_q,
                                             float* __restrict__ qv) {
    int cg = blockIdx.x, b = blockIdx.y;
    int t = threadIdx.x;
    int wid = t >> 6, lane = t & 63;
    // per-lane q segment (8 floats), coalesced 2KB per wave, L2-hot
    const float4* qrow = reinterpret_cast<const float4*>(q + (size_t)b*DQ);
    float4 q0 = qrow[lane*2], q1 = qrow[lane*2 + 1];
    #pragma unroll
    for (int r = 0; r < 4; ++r) {
        int c = cg*16 + wid*4 + r;
        const float4* wrow = reinterpret_cast<const float4*>(w_q + (size_t)c*DQ);
        float4 w0 = wrow[lane*2], w1 = wrow[lane*2 + 1];
        float acc = q0.x*w0.x + q0.y*w0.y + q0.z*w0.z + q0.w*w0.w
                  + q1.x*w1.x + q1.y*w1.y + q1.z*w1.z + q1.w*w1.w;
        #pragma unroll
        for (int k = 32; k > 0; k >>= 1) acc += __shfl_xor(acc, k);
        if (lane == 0) qv[b*DO + c] = acc + b_q[c];
    }
}

// ---------------------------------------------------------------- k2: fold qv into kc/kd weights (round-2 structure)
__global__ void k2_wqk(const float* __restrict__ qv,
                       const float* __restrict__ w_kc, const float* __restrict__ b_kc,
                       const float* __restrict__ w_kd, const float* __restrict__ b_kd,
                       const float* __restrict__ temp_c, const float* __restrict__ temp_d,
                       float* __restrict__ wqkc, float* __restrict__ wqkd,
                       float* __restrict__ qbc, float* __restrict__ qbd) {
    int bn = blockIdx.x;              // b*8 + n
    int n  = bn & 7;
    int t  = threadIdx.x;             // c
    __shared__ float qvs[DH];
    if (t < DH) qvs[t] = qv[(bn >> 3)*DO + n*DH + t];
    __syncthreads();
    float itc = 1.0f / temp_c[0];
    float itd = 1.0f / temp_d[0];
    float ac = 0.f, ad = 0.f;
    #pragma unroll
    for (int d = 0; d < DH; ++d) {
        float qd = qvs[d];
        ac += qd * w_kc[(n*DH + d)*DO + t];
        ad += qd * w_kd[(n*DH + d)*DO + t];
    }
    wqkc[bn*DO + t] = ac * itc;
    wqkd[bn*DO + t] = ad * itd;
    if (t == 0) {
        float sc = 0.f;
        for (int d = 0; d < DH; ++d) sc += qvs[d]*b_kc[n*DH + d];
        qbc[bn] = sc * itc;
    }
    if (t == 1) {
        float sd = 0.f;
        for (int d = 0; d < DH; ++d) sd += qvs[d]*b_kd[n*DH + d];
        qbd[bn] = sd * itd;
    }
}

// ---------------------------------------------------------------- k3: logits + gate + block-local softmax stats
// grid (NCH, B), block 512 (8 waves). 4 blocks/CU * 8 waves = 32 waves/CU.
__global__ __launch_bounds__(512, 8)
void k3(const float* __restrict__ v,
        const float* __restrict__ wqkc, const float* __restrict__ wqkd,
        const float* __restrict__ qbc,  const float* __restrict__ qbd,
        float* __restrict__ gate, float* __restrict__ ebuf, float* __restrict__ mz) {
    __shared__ float pc[8*NH*CHS];   // [csub][n][s]  16 KB
    __shared__ float pd[8*NH*CHS];   // 16 KB
    int ch = blockIdx.x, b = blockIdx.y;
    int t  = threadIdx.x;
    int s0 = ch*CHS;
    int bn0 = b*NH;
    int sl = t & 63;
    int csub = __builtin_amdgcn_readfirstlane(t >> 6);   // wave-uniform -> scalar weight loads

    // ---- phase 1: partial logits, csub-wave owns 32 channels, lanes over s (coalesced)
    {
        const float* vb = v + (size_t)b*DO*HW + s0 + sl;
        const float* wc = wqkc + bn0*DO;
        const float* wd = wqkd + bn0*DO;
        float ac[NH] = {0,0,0,0,0,0,0,0};
        float ad[NH] = {0,0,0,0,0,0,0,0};
        int cbase = csub*32;
        for (int c0 = cbase; c0 < cbase + 32; c0 += 4) {
            float v0 = vb[(size_t)(c0+0)*HW];
            float v1 = vb[(size_t)(c0+1)*HW];
            float v2 = vb[(size_t)(c0+2)*HW];
            float v3 = vb[(size_t)(c0+3)*HW];
            #pragma unroll
            for (int n = 0; n < NH; ++n) {
                ac[n] += v0*wc[n*DO+c0] + v1*wc[n*DO+c0+1] + v2*wc[n*DO+c0+2] + v3*wc[n*DO+c0+3];
                ad[n] += v0*wd[n*DO+c0] + v1*wd[n*DO+c0+1] + v2*wd[n*DO+c0+2] + v3*wd[n*DO+c0+3];
            }
        }
        #pragma unroll
        for (int n = 0; n < NH; ++n) {
            pc[(csub*NH + n)*CHS + sl] = ac[n];
            pd[(csub*NH + n)*CHS + sl] = ad[n];
        }
    }
    __syncthreads();

    // ---- phase 2: reduce csubs; wave n owns head n; gate + e + (m,z)
    {
        int n = csub, s = sl;
        float lc = qbc[bn0+n], ld = qbd[bn0+n];
        #pragma unroll
        for (int k = 0; k < 8; ++k) {
            lc += pc[(k*NH + n)*CHS + s];
            ld += pd[(k*NH + n)*CHS + s];
        }
        gate[(bn0+n)*HW + s0 + s] = 1.0f/(1.0f + __expf(-ld));
        float m = lc;
        #pragma unroll
        for (int k = 32; k > 0; k >>= 1) m = fmaxf(m, __shfl_xor(m, k));
        float e = __expf(lc - m);
        ebuf[(bn0+n)*HW + s0 + s] = e;
        float z = e;
        #pragma unroll
        for (int k = 32; k > 0; k >>= 1) z += __shfl_xor(z, k);
        if (s == 0) {
            float* mzp = mz + ((size_t)(b*NCH + ch)*NH + n)*2;
            mzp[0] = m; mzp[1] = z;
        }
    }
}

// ---------------------------------------------------------------- kP: normalized pool P[b,n,c] = sum over ALL s of p*v
// grid (8 c-groups, B), block 256 (4 waves); each wave 8 channel rows, 4 s-chunks each.
__global__ void kP(const float* __restrict__ v, const float* __restrict__ ebuf,
                   const float* __restrict__ mz, float* __restrict__ P) {
    __shared__ float p_lds[NH*HW];       // 32 KB normalized probs
    __shared__ float scale[NCH*NH];
    int cg = blockIdx.x, b = blockIdx.y;
    int t = threadIdx.x;
    if (t < NH) {
        int n = t;
        float M = -1e30f;
        for (int ch = 0; ch < NCH; ++ch)
            M = fmaxf(M, mz[((size_t)(b*NCH+ch)*NH+n)*2]);
        float Z = 0.f;
        for (int ch = 0; ch < NCH; ++ch) {
            float sc = __expf(mz[((size_t)(b*NCH+ch)*NH+n)*2] - M);
            Z += sc * mz[((size_t)(b*NCH+ch)*NH+n)*2 + 1];
            scale[ch*NH+n] = sc;
        }
        float inv = 1.0f/Z;
        for (int ch = 0; ch < NCH; ++ch) scale[ch*NH+n] *= inv;
    }
    __syncthreads();
    #pragma unroll
    for (int it = 0; it < 8; ++it) {
        int g = it*1024 + t*4;           // covers NH*HW = 8192 floats
        int n = g >> 10, s = g & 1023;
        float4 e4 = *reinterpret_cast<const float4*>(ebuf + (size_t)(b*NH+n)*HW + s);
        float sc = scale[(s>>6)*NH + n];
        *reinterpret_cast<float4*>(p_lds + g) = make_float4(e4.x*sc, e4.y*sc, e4.z*sc, e4.w*sc);
    }
    __syncthreads();
    int w = __builtin_amdgcn_readfirstlane(t >> 6), lane = t & 63;
    for (int r = 0; r < 8; ++r) {
        int c = cg*32 + w*8 + r;
        float red[NH] = {0,0,0,0,0,0,0,0};
        #pragma unroll
        for (int i4 = 0; i4 < 4; ++i4) {                 // full s range: 4 x 256
            int so = i4*256 + lane*4;
            float4 v4 = *reinterpret_cast<const float4*>(v + ((size_t)(b*DO+c))*HW + so);
            #pragma unroll
            for (int n = 0; n < NH; ++n) {
                float4 p4 = *reinterpret_cast<const float4*>(p_lds + n*HW + so);
                red[n] += v4.x*p4.x + v4.y*p4.y + v4.z*p4.z + v4.w*p4.w;
            }
        }
        #pragma unroll
        for (int n = 0; n < NH; ++n) {
            float x = red[n];
            #pragma unroll
            for (int k = 32; k > 0; k >>= 1) x += __shfl_xor(x, k);
            red[n] = x;
        }
        if (lane == 0) {
            #pragma unroll
            for (int n = 0; n < NH; ++n) P[(size_t)(b*NH+n)*DO + c] = red[n];
        }
    }
}

// ---------------------------------------------------------------- k4c: attn = w_v . P + b_v
__global__ void k4c(const float* __restrict__ P, const float* __restrict__ w_v,
                    const float* __restrict__ b_v, float* __restrict__ attn) {
    __shared__ float pv_lds[NH*DO];
    int b = blockIdx.x, t = threadIdx.x;
    for (int i = t; i < NH*DO; i += 256) pv_lds[i] = P[(size_t)b*NH*DO + i];
    __syncthreads();
    int n = t >> 5;
    float acc = b_v[t];
    const float4* w4 = reinterpret_cast<const float4*>(w_v + t*DO);
    #pragma unroll 4
    for (int c4 = 0; c4 < DO/4; ++c4) {
        float4 wv = w4[c4];
        int c = c4*4;
        acc += pv_lds[n*DO+c]*wv.x + pv_lds[n*DO+c+1]*wv.y + pv_lds[n*DO+c+2]*wv.z + pv_lds[n*DO+c+3]*wv.w;
    }
    attn[b*DO + t] = acc;
}

// ---------------------------------------------------------------- k5: out = leaky(bn(gate[s^T]*attn + v))
__global__ void k5_out(const float* __restrict__ v, const float* __restrict__ gate,
                       const float* __restrict__ attn,
                       const float* __restrict__ bn_g, const float* __restrict__ bn_b,
                       const float* __restrict__ bn_m, const float* __restrict__ bn_v,
                       float* __restrict__ out) {
    int c = blockIdx.x, b = blockIdx.y;
    int n = c >> 5, d = c & 31;
    int t = threadIdx.x;
    __shared__ float g[32*33];             // stride 33 kills transpose bank conflicts
    float4 gv = reinterpret_cast<const float4*>(gate + (b*NH + n)*HW)[t];
    int s0 = t*4;
    int ga = s0 >> 5, gb = s0 & 31;
    g[ga*33 + gb + 0] = gv.x;
    g[ga*33 + gb + 1] = gv.y;
    g[ga*33 + gb + 2] = gv.z;
    g[ga*33 + gb + 3] = gv.w;
    __syncthreads();
    float av   = attn[(b*NH + n)*DH + d];
    float inv  = bn_g[c] / sqrtf(bn_v[c] + 1e-5f);
    float mean = bn_m[c], beta = bn_b[c];
    size_t base = ((size_t)(b*DO + c))*HW;
    float4 r4 = reinterpret_cast<const float4*>(v + base)[t];
    int l = 4*t;
    int i_ = l >> 5, j_ = l & 31;          // gate index s = j*32 + i
    float x0 = g[(j_+0)*33 + i_]*av + r4.x;
    float x1 = g[(j_+1)*33 + i_]*av + r4.y;
    float x2 = g[(j_+2)*33 + i_]*av + r4.z;
    float x3 = g[(j_+3)*33 + i_]*av + r4.w;
    float y0 = (x0 - mean)*inv + beta; y0 = y0 >= 0.f ? y0 : 0.1f*y0;
    float y1 = (x1 - mean)*inv + beta; y1 = y1 >= 0.f ? y1 : 0.1f*y1;
    float y2 = (x2 - mean)*inv + beta; y2 = y2 >= 0.f ? y2 : 0.1f*y2;
    float y3 = (x3 - mean)*inv + beta; y3 = y3 >= 0.f ? y3 : 0.1f*y3;
    reinterpret_cast<float4*>(out + base)[t] = make_float4(y0, y1, y2, y3);
}

// ----------------------------------------------------------------
extern "C" void kernel_launch(void* const* d_in, const int* in_sizes, int n_in,
                              void* d_out, int out_size, void* d_ws, size_t ws_size,
                              hipStream_t stream) {
    const float* q      = (const float*)d_in[0];
    const float* v      = (const float*)d_in[1];
    const float* w_q    = (const float*)d_in[2];
    const float* b_q    = (const float*)d_in[3];
    const float* w_kc   = (const float*)d_in[4];
    const float* b_kc   = (const float*)d_in[5];
    const float* w_kd   = (const float*)d_in[6];
    const float* b_kd   = (const float*)d_in[7];
    const float* w_v    = (const float*)d_in[8];
    const float* b_v    = (const float*)d_in[9];
    const float* temp_c = (const float*)d_in[10];
    const float* temp_d = (const float*)d_in[11];
    const float* bn_g   = (const float*)d_in[12];
    const float* bn_b   = (const float*)d_in[13];
    const float* bn_m   = (const float*)d_in[14];
    const float* bn_v   = (const float*)d_in[15];
    float* out = (float*)d_out;

    float* ws   = (float*)d_ws;
    float* qv   = ws;                     // B*DO        = 16384
    float* wqkc = qv   + B*DO;            // B*NH*DO     = 131072
    float* wqkd = wqkc + B*NH*DO;         // 131072
    float* qbc  = wqkd + B*NH*DO;         // 512
    float* qbd  = qbc  + B*NH;            // 512
    float* gate = qbd  + B*NH;            // B*NH*HW     = 524288
    float* ebuf = gate + B*NH*HW;         // 524288
    float* mz   = ebuf + B*NH*HW;         // B*NCH*NH*2  = 16384
    float* P    = mz   + B*NCH*NH*2;      // B*NH*DO     = 131072
    float* attn = P    + B*NH*DO;         // B*DO        = 16384

    k1_qv <<<dim3(16, B),   256, 0, stream>>>(q, w_q, b_q, qv);
    k2_wqk<<<B*NH,          256, 0, stream>>>(qv, w_kc, b_kc, w_kd, b_kd, temp_c, temp_d,
                                              wqkc, wqkd, qbc, qbd);
    k3    <<<dim3(NCH, B),  512, 0, stream>>>(v, wqkc, wqkd, qbc, qbd, gate, ebuf, mz);
    kP    <<<dim3(8, B),    256, 0, stream>>>(v, ebuf, mz, P);
    k4c   <<<B,             256, 0, stream>>>(P, w_v, b_v, attn);
    k5_out<<<dim3(DO, B),   256, 0, stream>>>(v, gate, attn, bn_g, bn_b, bn_m, bn_v, out);
}